// Round 6
// baseline (587.842 us; speedup 1.0000x reference)
//
#include <hip/hip_runtime.h>
#include <hip/hip_cooperative_groups.h>
#include <hip/hip_bf16.h>
#include <math.h>

#define BN 256
#define NN 2048
#define CC 64
#define NSEG 8            // 256-row segments per batch row
#define SEGR 256
#define NT (BN * NSEG)    // 2048 tiles per streaming phase
#define NBLK 256          // grid size (== CU count, cooperative)

// workspace float offsets (no memset: deterministic per-tile partial slots)
#define WS_SUMQP 0                               // [BN][NSEG][64]
#define WS_SUMMP (WS_SUMQP + BN * NSEG * 64)     // [BN][NSEG]
#define WS_VP    (WS_SUMMP + BN * NSEG)          // [BN][NSEG][64]
#define WS_SP    (WS_VP + BN * NSEG * 64)        // [BN][NSEG][8]
#define WS_KQ    (WS_SP + BN * NSEG * 8)         // [BN][64*8] kq[b][c][h]
#define WS_WAVG  (WS_KQ + BN * 512)              // [BN][64]  V/S (pre-divided)
#define WS_MASK  (WS_WAVG + BN * 64)             // [BN][NN]  compact mask

typedef __bf16 bf16x8 __attribute__((ext_vector_type(8)));
typedef float f32x4 __attribute__((ext_vector_type(4)));

namespace cg = cooperative_groups;

// Narrow-front cooperative kernel. All streaming phases iterate b-major
// 256-row tiles with tile->block = tile % NBLK, so the 256 resident blocks
// read ADJACENT 64KB tiles (instantaneous front ~16MB) instead of private
// 512KB windows -- the experiment: do interleaved reads reach >>2.2 TB/s?
__global__ __launch_bounds__(1024, 4) void k_all(
    const float* __restrict__ qd, const float* __restrict__ md,
    const float* __restrict__ qm, const float* __restrict__ qw,
    const float* __restrict__ kw, const float* __restrict__ vw,
    const float* __restrict__ ow, const float* __restrict__ obias,
    const float* __restrict__ gw, const float* __restrict__ gb,
    float* __restrict__ ws, float* __restrict__ out) {
    cg::grid_group grid = cg::this_grid();
    const int bid = blockIdx.x, tid = threadIdx.x;

    __shared__ float lm[SEGR];                    // 1 KB
    __shared__ float lmw[4];
    __shared__ float red[64][64];                 // 16 KB
    __shared__ float wkv[64][16];                 // 4 KB (phys-row swizzled)
    __shared__ float PVF_[SEGR * 17];             // 17.4 KB
    __shared__ float partC[16][72];               // 4.6 KB
    __shared__ float qa[64], ql[64], swavg[64];
    __shared__ __align__(16) __bf16 gwT[4096];    // 8 KB swizzled [n][k]
    __shared__ __align__(16) __bf16 owT[4096];    // 8 KB swizzled [n][k]
    __shared__ __align__(16) __bf16 gl[16][16][72];  // 36.9 KB transpose buf

    // ================= phase A: pool partials + mask compaction ============
#pragma unroll 1
    for (int t = bid; t < NT; t += NBLK) {
        const int b = t >> 3, seg = t & 7;
        const size_t grow0 = (size_t)b * NN + (size_t)seg * SEGR;
        if (tid < SEGR) {
            const float m = qm[(grow0 + tid) * CC];  // channel-0 broadcast mask
            lm[tid] = m;
            ws[WS_MASK + grow0 + tid] = m;
            float s = m;
            for (int off = 32; off > 0; off >>= 1) s += __shfl_down(s, off, 64);
            if ((tid & 63) == 0) lmw[tid >> 6] = s;
        }
        const float4* qb4 = (const float4*)(qd + grow0 * CC);
        const float4 v0 = qb4[tid], v1 = qb4[tid + 1024];
        const float4 v2 = qb4[tid + 2048], v3 = qb4[tid + 3072];
        __syncthreads();
        const int rg = tid >> 4;
        const float m0 = lm[rg], m1 = lm[rg + 64], m2 = lm[rg + 128], m3 = lm[rg + 192];
        float4 acc;
        acc.x = m0 * v0.x + m1 * v1.x + m2 * v2.x + m3 * v3.x;
        acc.y = m0 * v0.y + m1 * v1.y + m2 * v2.y + m3 * v3.y;
        acc.z = m0 * v0.z + m1 * v1.z + m2 * v2.z + m3 * v3.z;
        acc.w = m0 * v0.w + m1 * v1.w + m2 * v2.w + m3 * v3.w;
        *(float4*)&red[rg][(tid & 15) * 4] = acc;
        __syncthreads();
        if (tid < 64) {
            float s = 0.f;
#pragma unroll
            for (int g = 0; g < 64; ++g) s += red[g][tid];
            ws[WS_SUMQP + (size_t)t * 64 + tid] = s;
        }
        if (tid == 0) ws[WS_SUMMP + t] = lmw[0] + lmw[1] + lmw[2] + lmw[3];
        __syncthreads();  // protect lm/red/lmw for next tile
    }
    grid.sync();

    // ================= phase B: per-b q_avg -> q -> kq (b = bid) ===========
    {
        const int b = bid;
        if (tid < 64) {
            float s = 0.f, den = 0.f;
#pragma unroll
            for (int g = 0; g < NSEG; ++g) {
                s += ws[WS_SUMQP + (size_t)(b * NSEG + g) * 64 + tid];
                den += ws[WS_SUMMP + b * NSEG + g];
            }
            qa[tid] = s / (den + 1e-10f);
        }
        __syncthreads();
        if (tid < 64) {
            float s = 0.f;
#pragma unroll
            for (int c = 0; c < 64; ++c) s += qa[c] * qw[c * 64 + tid];
            ql[tid] = s * 0.35355339059327373f;  // KD^-0.5, KD=8
        }
        __syncthreads();
        if (tid < 512) {
            const int c = tid >> 3, h = tid & 7;
            float s = 0.f;
#pragma unroll
            for (int d = 0; d < 8; ++d) s += kw[c * 8 + d] * ql[h * 8 + d];
            ws[WS_KQ + (size_t)b * 512 + tid] = s;
        }
    }
    grid.sync();

    // ================= phase C: attention partials =========================
    // 4 threads per row (16 channels each) -> shfl combine -> P/V staged ->
    // block reduce -> per-tile partial slot. wkv phys row = ((c&15)<<2)|(c>>4)
    // so the 4 lane-groups hit different banks.
#define C_Q(xv, PRROW)                                                        \
    {                                                                         \
        const float4* wr = (const float4*)wkv[PRROW];                         \
        const float4 wa = wr[0], wb = wr[1], wc = wr[2], wd = wr[3];          \
        la[0] += (xv)*wa.x; la[1] += (xv)*wa.y; la[2] += (xv)*wa.z; la[3] += (xv)*wa.w; \
        la[4] += (xv)*wb.x; la[5] += (xv)*wb.y; la[6] += (xv)*wb.z; la[7] += (xv)*wb.w; \
        va[0] += (xv)*wc.x; va[1] += (xv)*wc.y; va[2] += (xv)*wc.z; va[3] += (xv)*wc.w; \
        va[4] += (xv)*wd.x; va[5] += (xv)*wd.y; va[6] += (xv)*wd.z; va[7] += (xv)*wd.w; \
    }
#define C_U(XB, U)                                    \
    C_Q(XB.x, (((U)*4 + 0) << 2) | cg4)               \
    C_Q(XB.y, (((U)*4 + 1) << 2) | cg4)               \
    C_Q(XB.z, (((U)*4 + 2) << 2) | cg4)               \
    C_Q(XB.w, (((U)*4 + 3) << 2) | cg4)

#pragma unroll 1
    for (int t = bid; t < NT; t += NBLK) {
        const int b = t >> 3, seg = t & 7;
        const size_t grow0 = (size_t)b * NN + (size_t)seg * SEGR;
        if (tid < 512) {
            const int c = tid >> 3, h = tid & 7;
            const int pr = ((c & 15) << 2) | (c >> 4);
            wkv[pr][h] = ws[WS_KQ + (size_t)b * 512 + tid];
            wkv[pr][8 + h] = vw[tid];
        }
        const int row = tid >> 2, cg4 = tid & 3;
        const size_t gr = grow0 + row;
        const float mk = ws[WS_MASK + gr];
        const float4* rp = (const float4*)(md + gr * CC) + cg4 * 4;
        const float4 xb0 = rp[0], xb1 = rp[1], xb2 = rp[2], xb3 = rp[3];
        __syncthreads();  // wkv ready
        float la[8] = {0.f, 0.f, 0.f, 0.f, 0.f, 0.f, 0.f, 0.f};
        float va[8] = {0.f, 0.f, 0.f, 0.f, 0.f, 0.f, 0.f, 0.f};
        C_U(xb0, 0) C_U(xb1, 1) C_U(xb2, 2) C_U(xb3, 3)
#pragma unroll
        for (int h = 0; h < 8; ++h) {
            la[h] += __shfl_xor(la[h], 1, 64); la[h] += __shfl_xor(la[h], 2, 64);
            va[h] += __shfl_xor(va[h], 1, 64); va[h] += __shfl_xor(va[h], 2, 64);
        }
        if (cg4 == 0) {
#pragma unroll
            for (int h = 0; h < 8; ++h) {
                PVF_[row * 17 + h] = mk * __expf(la[h]);  // masked rows -> 0
                PVF_[row * 17 + 8 + h] = va[h];
            }
        }
        __syncthreads();
        {
            const int w = tid >> 6, lane = tid & 63, hh = lane >> 3, dd = lane & 7;
            float a2 = 0.f, s2 = 0.f;
#pragma unroll
            for (int i = 0; i < 16; ++i) {
                const int rr = w * 16 + i;
                const float p = PVF_[rr * 17 + hh];
                a2 += p * PVF_[rr * 17 + 8 + dd];
                s2 += p;
            }
            partC[w][lane] = a2;
            if (dd == 0) partC[w][64 + hh] = s2;
        }
        __syncthreads();
        if (tid < 64) {
            float s = 0.f;
#pragma unroll
            for (int g = 0; g < 16; ++g) s += partC[g][tid];
            ws[WS_VP + (size_t)t * 64 + tid] = s;
        }
        if (tid < 8) {
            float s = 0.f;
#pragma unroll
            for (int g = 0; g < 16; ++g) s += partC[g][64 + tid];
            ws[WS_SP + (size_t)t * 8 + tid] = s;
        }
        __syncthreads();  // protect PVF/partC/wkv for next tile
    }
    grid.sync();

    // ================= phase C2: reduce V/S -> wavg (b = bid) ==============
    {
        const int b = bid;
        if (tid < 64) {
            float v = 0.f, s = 0.f;
#pragma unroll
            for (int g = 0; g < NSEG; ++g) {
                v += ws[WS_VP + (size_t)(b * NSEG + g) * 64 + tid];
                s += ws[WS_SP + (size_t)(b * NSEG + g) * 8 + (tid >> 3)];
            }
            ws[WS_WAVG + (size_t)b * 64 + tid] = v / s;
        }
    }
    grid.sync();

    // ================= phase D: gate (MFMA) + output (MFMA) ================
    {
        const int k = tid >> 4, n0 = (tid & 15) * 4;
#pragma unroll
        for (int u = 0; u < 4; ++u) {
            const int n = n0 + u;
            const int idx = n * 64 + (((k >> 3) ^ (n & 7)) << 3) + (k & 7);
            gwT[idx] = (__bf16)gw[(size_t)k * 64 + n];
            owT[idx] = (__bf16)ow[(size_t)k * 64 + n];
        }
    }
    const int w = tid >> 6, lane = tid & 63, q16 = lane >> 4, c16 = lane & 15;
    float gbv[4], obv[4];
#pragma unroll
    for (int tt = 0; tt < 4; ++tt) {
        gbv[tt] = gb[tt * 16 + c16];
        obv[tt] = obias[tt * 16 + c16];
    }
    float4 cur0, cur1, cur2, cur3, nxt0, nxt1, nxt2, nxt3;
    {
        const size_t br = (size_t)(bid >> 3) * NN + (size_t)(bid & 7) * SEGR + w * 16;
        const float* arow = qd + (br + c16) * CC;
        cur0 = *(const float4*)(arow + q16 * 8);
        cur1 = *(const float4*)(arow + q16 * 8 + 4);
        cur2 = *(const float4*)(arow + 32 + q16 * 8);
        cur3 = *(const float4*)(arow + 32 + q16 * 8 + 4);
    }
#pragma unroll 1
    for (int t = bid; t < NT; t += NBLK) {
        if (tid < 64) swavg[tid] = ws[WS_WAVG + (size_t)(t >> 3) * 64 + tid];
        __syncthreads();  // swavg (and first-iter gwT/owT) ready
        if (t + NBLK < NT) {  // prefetch next tile's slab rows
            const int tn = t + NBLK;
            const size_t br = (size_t)(tn >> 3) * NN + (size_t)(tn & 7) * SEGR + w * 16;
            const float* arow = qd + (br + c16) * CC;
            nxt0 = *(const float4*)(arow + q16 * 8);
            nxt1 = *(const float4*)(arow + q16 * 8 + 4);
            nxt2 = *(const float4*)(arow + 32 + q16 * 8);
            nxt3 = *(const float4*)(arow + 32 + q16 * 8 + 4);
        }
        float wv[4];
#pragma unroll
        for (int tt = 0; tt < 4; ++tt) wv[tt] = swavg[tt * 16 + c16];

        bf16x8 af[2];
        {
            bf16x8 a;
            a[0] = (__bf16)cur0.x; a[1] = (__bf16)cur0.y; a[2] = (__bf16)cur0.z; a[3] = (__bf16)cur0.w;
            a[4] = (__bf16)cur1.x; a[5] = (__bf16)cur1.y; a[6] = (__bf16)cur1.z; a[7] = (__bf16)cur1.w;
            af[0] = a;
            a[0] = (__bf16)cur2.x; a[1] = (__bf16)cur2.y; a[2] = (__bf16)cur2.z; a[3] = (__bf16)cur2.w;
            a[4] = (__bf16)cur3.x; a[5] = (__bf16)cur3.y; a[6] = (__bf16)cur3.z; a[7] = (__bf16)cur3.w;
            af[1] = a;
        }
        f32x4 accg[4] = {{0.f, 0.f, 0.f, 0.f}, {0.f, 0.f, 0.f, 0.f},
                         {0.f, 0.f, 0.f, 0.f}, {0.f, 0.f, 0.f, 0.f}};
#pragma unroll
        for (int kc = 0; kc < 2; ++kc) {
            bf16x8 bf[4];
#pragma unroll
            for (int tt = 0; tt < 4; ++tt) {
                const int n = tt * 16 + c16;
                bf[tt] = *(const bf16x8*)&gwT[n * 64 + (((kc * 4 + q16) ^ (n & 7)) << 3)];
            }
#pragma unroll
            for (int tt = 0; tt < 4; ++tt)
                accg[tt] = __builtin_amdgcn_mfma_f32_16x16x32_bf16(af[kc], bf[tt],
                                                                   accg[tt], 0, 0, 0);
        }
        // sigmoid, scale by wavg (k of the 2nd matmul == col of the 1st), stash
#pragma unroll
        for (int tt = 0; tt < 4; ++tt)
#pragma unroll
            for (int r2 = 0; r2 < 4; ++r2) {
                const float x = accg[tt][r2] + gbv[tt];
                const float g = 1.f / (1.f + __expf(-x));
                gl[w][q16 * 4 + r2][tt * 16 + c16] = (__bf16)(g * wv[tt]);
            }
        __asm__ volatile("s_waitcnt lgkmcnt(0)" ::: "memory");
        bf16x8 a2[2];
#pragma unroll
        for (int kc = 0; kc < 2; ++kc)
            a2[kc] = *(const bf16x8*)&gl[w][c16][kc * 32 + q16 * 8];
        f32x4 acco[4] = {{0.f, 0.f, 0.f, 0.f}, {0.f, 0.f, 0.f, 0.f},
                         {0.f, 0.f, 0.f, 0.f}, {0.f, 0.f, 0.f, 0.f}};
#pragma unroll
        for (int kc = 0; kc < 2; ++kc) {
            bf16x8 bf[4];
#pragma unroll
            for (int tt = 0; tt < 4; ++tt) {
                const int n = tt * 16 + c16;
                bf[tt] = *(const bf16x8*)&owT[n * 64 + (((kc * 4 + q16) ^ (n & 7)) << 3)];
            }
#pragma unroll
            for (int tt = 0; tt < 4; ++tt)
                acco[tt] = __builtin_amdgcn_mfma_f32_16x16x32_bf16(a2[kc], bf[tt],
                                                                   acco[tt], 0, 0, 0);
        }
        __asm__ volatile("s_waitcnt lgkmcnt(0)" ::: "memory");  // gl reads done
        {
            const size_t br = (size_t)(t >> 3) * NN + (size_t)(t & 7) * SEGR + w * 16;
            float* orow = out + br * CC;
#pragma unroll
            for (int tt = 0; tt < 4; ++tt)
#pragma unroll
                for (int r2 = 0; r2 < 4; ++r2)
                    orow[(size_t)(q16 * 4 + r2) * 64 + tt * 16 + c16] =
                        acco[tt][r2] + obv[tt];
        }
        __syncthreads();  // swavg consumed before next tile's overwrite
        cur0 = nxt0; cur1 = nxt1; cur2 = nxt2; cur3 = nxt3;
    }
#undef C_U
#undef C_Q
}

extern "C" void kernel_launch(void* const* d_in, const int* in_sizes, int n_in,
                              void* d_out, int out_size, void* d_ws, size_t ws_size,
                              hipStream_t stream) {
    const float* q_data = (const float*)d_in[0];
    const float* m_data = (const float*)d_in[1];
    const float* q_mask = (const float*)d_in[2];
    // d_in[3] = bias, ignored by the forward (AF2 quirk)
    const float* q_w = (const float*)d_in[4];
    const float* k_w = (const float*)d_in[5];
    const float* v_w = (const float*)d_in[6];
    const float* o_w = (const float*)d_in[7];
    const float* o_b = (const float*)d_in[8];
    const float* g_w = (const float*)d_in[9];
    const float* g_b = (const float*)d_in[10];
    float* out = (float*)d_out;
    float* ws = (float*)d_ws;
    (void)in_sizes; (void)n_in; (void)out_size; (void)ws_size;

    void* args[] = {(void*)&q_data, (void*)&m_data, (void*)&q_mask, (void*)&q_w,
                    (void*)&k_w,    (void*)&v_w,    (void*)&o_w,    (void*)&o_b,
                    (void*)&g_w,    (void*)&g_b,    (void*)&ws,     (void*)&out};
    hipLaunchCooperativeKernel((const void*)k_all, dim3(NBLK), dim3(1024), args, 0,
                               stream);
}

// Round 7
// 449.184 us; speedup vs baseline: 1.3087x; 1.3087x over previous
//
#include <hip/hip_runtime.h>
#include <hip/hip_bf16.h>
#include <math.h>

#define BN 256
#define NN 2048
#define CC 64

typedef __bf16 bf16x8 __attribute__((ext_vector_type(8)));
typedef float f32x4 __attribute__((ext_vector_type(4)));

// ============ single fused kernel: block b owns batch b entirely ============
// 256 blocks x 1024 threads (16 waves). LDS ~69 KB + VGPR<=64 -> 2 blocks/CU
// (32 waves), so one block's loads overlap the other's compute.
// Phase 0: mask channel-0 -> LDS.
// Phase 1: masked pool of q_data[b] (512KB contiguous sweep, 8-deep batches).
// Phase 2: q_avg -> q -> kq (bf16) || stage gwT/owT (waves 8-15).
// Phase 3: attention as MFMA GEMM [2048x64]@[64x16] (cols 0-7 logits, 8-15
//          v-proj): per wave-step 4 float4 -> A-frag, hoisted B-frag, 2 MFMA,
//          stage p=mask*exp(la) | va to PV[256][17], block-reduce into regs.
// Phase 4: gate = sigmoid(q_data@Gw+gb) via MFMA, scaled by wavg; out = @Ow+ob.
// pool (36.9KB) is reused: phase-1 red[64][64] / phase-3 PV[256][17] /
// phase-4 gl[16][16][72] (all separated by barriers).
__global__ __launch_bounds__(1024, 8) void k_fused(
    const float* __restrict__ qd, const float* __restrict__ md,
    const float* __restrict__ qm, const float* __restrict__ qw,
    const float* __restrict__ kw, const float* __restrict__ vw,
    const float* __restrict__ ow, const float* __restrict__ obias,
    const float* __restrict__ gw, const float* __restrict__ gb,
    float* __restrict__ out) {
    const int b = blockIdx.x, tid = threadIdx.x;
    const int w = tid >> 6, lane = tid & 63, q16 = lane >> 4, c16 = lane & 15;

    __shared__ float smask[2048];                    // 8 KB
    __shared__ __align__(16) float pool[9216];       // 36.9 KB (red/PV/gl)
    __shared__ float partV[16][64];                  // 4 KB
    __shared__ float partS[16][8];                   // 0.5 KB
    __shared__ float qa[64], ql[64], s_wavg[64];     // 0.75 KB
    __shared__ __bf16 wkvB[64][16];                  // 2 KB  [c][0..7]=kq,[8..15]=vw
    __shared__ __align__(16) __bf16 gwT[4096];       // 8 KB swizzled [n][k]
    __shared__ __align__(16) __bf16 owT[4096];       // 8 KB swizzled [n][k]

#define RED(g, c) pool[(g) * 64 + (c)]
#define PVF(n, j) pool[(n) * 17 + (j)]

    // ---- phase 0: mask channel-0 (stride 256B) into LDS
    smask[tid] = qm[((size_t)b * NN + tid) * CC];
    smask[tid + 1024] = qm[((size_t)b * NN + tid + 1024) * CC];
    __syncthreads();

    // ---- phase 1: masked pool, sequential 512KB sweep, 8-deep batches
    {
        const float4* qb4 = (const float4*)(qd + (size_t)b * NN * CC);
        const int rbase = tid >> 4;  // row-within-step
        float4 acc = {0.f, 0.f, 0.f, 0.f};
        for (int g4 = 0; g4 < 4; ++g4) {
            float4 v[8];
#pragma unroll
            for (int j = 0; j < 8; ++j)
                v[j] = qb4[(size_t)(g4 * 8 + j) * 1024 + tid];  // max 32767
#pragma unroll
            for (int j = 0; j < 8; ++j) {
                const float m = smask[(g4 * 8 + j) * 64 + rbase];  // max 2047
                acc.x += m * v[j].x; acc.y += m * v[j].y;
                acc.z += m * v[j].z; acc.w += m * v[j].w;
            }
        }
        *(float4*)&RED(rbase, (tid & 15) * 4) = acc;
    }
    __syncthreads();

    // ---- phase 2: q_avg -> q -> kq(bf16); waves 8-15 stage gwT/owT
    if (tid < 64) {
        float den = 0.f;
        for (int g = 0; g < 32; ++g) den += smask[tid + g * 64];
        for (int off = 1; off < 64; off <<= 1) den += __shfl_xor(den, off, 64);
        float s = 0.f;
        for (int g = 0; g < 64; ++g) s += RED(g, tid);
        qa[tid] = s / (den + 1e-10f);
    } else if (tid >= 512) {
        // swizzle: (k,n) -> n*64 + ((k>>3)^(n&7))*8 + (k&7)
        const int k = (tid - 512) >> 3, n0 = (tid & 7) * 8;
#pragma unroll
        for (int u = 0; u < 8; ++u) {
            const int n = n0 + u;
            const int idx = n * 64 + (((k >> 3) ^ (n & 7)) << 3) + (k & 7);
            gwT[idx] = (__bf16)gw[(size_t)k * 64 + n];
            owT[idx] = (__bf16)ow[(size_t)k * 64 + n];
        }
    }
    __syncthreads();
    if (tid < 64) {
        float s = 0.f;
#pragma unroll
        for (int c = 0; c < 64; ++c) s += qa[c] * qw[c * 64 + tid];
        ql[tid] = s * 0.35355339059327373f;  // KD^-0.5, KD=8
    }
    __syncthreads();
    if (tid < 512) {
        const int c = tid >> 3, h = tid & 7;
        float s = 0.f;
#pragma unroll
        for (int d = 0; d < 8; ++d) s += kw[c * 8 + d] * ql[h * 8 + d];
        wkvB[c][h] = (__bf16)s;
        wkvB[c][8 + h] = (__bf16)vw[tid];  // vw[c][h]
    }
    __syncthreads();

    // ---- phase 3: attention as MFMA. B-frag (loop-invariant) hoisted:
    // B[k=kc*32+q16*8+j][n=c16]
    bf16x8 bkq[2];
#pragma unroll
    for (int kc = 0; kc < 2; ++kc)
#pragma unroll
        for (int j = 0; j < 8; ++j) bkq[kc][j] = wkvB[kc * 32 + q16 * 8 + j][c16];

    float accV = 0.f, accS = 0.f;
#pragma unroll 1
    for (int s = 0; s < 8; ++s) {
        const int r0 = s * 256 + w * 16;  // this wave's 16 rows
        const float* arow = md + ((size_t)b * NN + r0 + c16) * CC;
        const float4 x0 = *(const float4*)(arow + q16 * 8);
        const float4 x1 = *(const float4*)(arow + q16 * 8 + 4);
        const float4 x2 = *(const float4*)(arow + 32 + q16 * 8);
        const float4 x3 = *(const float4*)(arow + 32 + q16 * 8 + 4);
        bf16x8 af[2];
        {
            bf16x8 a;
            a[0] = (__bf16)x0.x; a[1] = (__bf16)x0.y; a[2] = (__bf16)x0.z; a[3] = (__bf16)x0.w;
            a[4] = (__bf16)x1.x; a[5] = (__bf16)x1.y; a[6] = (__bf16)x1.z; a[7] = (__bf16)x1.w;
            af[0] = a;
            a[0] = (__bf16)x2.x; a[1] = (__bf16)x2.y; a[2] = (__bf16)x2.z; a[3] = (__bf16)x2.w;
            a[4] = (__bf16)x3.x; a[5] = (__bf16)x3.y; a[6] = (__bf16)x3.z; a[7] = (__bf16)x3.w;
            af[1] = a;
        }
        f32x4 acc = {0.f, 0.f, 0.f, 0.f};
        acc = __builtin_amdgcn_mfma_f32_16x16x32_bf16(af[0], bkq[0], acc, 0, 0, 0);
        acc = __builtin_amdgcn_mfma_f32_16x16x32_bf16(af[1], bkq[1], acc, 0, 0, 0);
        // D[row=q16*4+r][col=c16]; cols 0-7 logits -> p = mask*exp, 8-15 raw va
#pragma unroll
        for (int r = 0; r < 4; ++r) {
            const int rl = q16 * 4 + r;
            const float dv = acc[r];
            const float pexp = smask[r0 + rl] * __expf(dv);
            PVF(w * 16 + rl, c16) = (c16 < 8) ? pexp : dv;
        }
        __syncthreads();
        {
            const int h = lane >> 3, d = lane & 7;
#pragma unroll
            for (int i = 0; i < 16; ++i) {
                const int rr = w * 16 + i;
                const float p = PVF(rr, h);  // 8-addr broadcast, conflict-free
                accV += p * PVF(rr, 8 + d);
                accS += p;
            }
        }
        __syncthreads();  // PV reads done before next step's writes
    }
    partV[w][lane] = accV;
    if ((lane & 7) == 0) partS[w][lane >> 3] = accS;
    __syncthreads();

    // ---- phase 4 prep: wavg = V/S; first A-slab prefetch overlaps
    const size_t base_row = (size_t)b * NN + (size_t)w * 128;
    float4 cur0, cur1, cur2, cur3, nxt0, nxt1, nxt2, nxt3;
    {
        const float* arow = qd + (base_row + c16) * CC;
        cur0 = *(const float4*)(arow + q16 * 8);
        cur1 = *(const float4*)(arow + q16 * 8 + 4);
        cur2 = *(const float4*)(arow + 32 + q16 * 8);
        cur3 = *(const float4*)(arow + 32 + q16 * 8 + 4);
    }
    if (tid < 64) {
        float v = 0.f, ss = 0.f;
#pragma unroll
        for (int g = 0; g < 16; ++g) {
            v += partV[g][tid];
            ss += partS[g][tid >> 3];
        }
        s_wavg[tid] = v / ss;
    }
    __syncthreads();  // s_wavg ready; all pool reads retired -> gl alias safe

    // ---- phase 4: wave w owns rows w*128..+127, 8 slabs of 16 rows
    __bf16* gl = (__bf16*)pool;  // [16][16][72] view, wave-private slice
#define GL(wv, r, c) gl[(((wv)*16 + (r)) * 72) + (c)]
    float gbv[4], obv[4], wv[4];
#pragma unroll
    for (int tt = 0; tt < 4; ++tt) {
        gbv[tt] = gb[tt * 16 + c16];
        obv[tt] = obias[tt * 16 + c16];
        wv[tt] = s_wavg[tt * 16 + c16];
    }

    for (int s = 0; s < 8; ++s) {
        if (s < 7) {  // prefetch next slab
            const float* arow = qd + (base_row + (s + 1) * 16 + c16) * CC;
            nxt0 = *(const float4*)(arow + q16 * 8);
            nxt1 = *(const float4*)(arow + q16 * 8 + 4);
            nxt2 = *(const float4*)(arow + 32 + q16 * 8);
            nxt3 = *(const float4*)(arow + 32 + q16 * 8 + 4);
        }
        bf16x8 af[2];
        {
            bf16x8 a;
            a[0] = (__bf16)cur0.x; a[1] = (__bf16)cur0.y; a[2] = (__bf16)cur0.z; a[3] = (__bf16)cur0.w;
            a[4] = (__bf16)cur1.x; a[5] = (__bf16)cur1.y; a[6] = (__bf16)cur1.z; a[7] = (__bf16)cur1.w;
            af[0] = a;
            a[0] = (__bf16)cur2.x; a[1] = (__bf16)cur2.y; a[2] = (__bf16)cur2.z; a[3] = (__bf16)cur2.w;
            a[4] = (__bf16)cur3.x; a[5] = (__bf16)cur3.y; a[6] = (__bf16)cur3.z; a[7] = (__bf16)cur3.w;
            af[1] = a;
        }
        f32x4 accg[4] = {{0.f, 0.f, 0.f, 0.f}, {0.f, 0.f, 0.f, 0.f},
                         {0.f, 0.f, 0.f, 0.f}, {0.f, 0.f, 0.f, 0.f}};
#pragma unroll
        for (int kc = 0; kc < 2; ++kc) {
            bf16x8 bf[4];
#pragma unroll
            for (int tt = 0; tt < 4; ++tt) {
                const int n = tt * 16 + c16;
                bf[tt] = *(const bf16x8*)&gwT[n * 64 + (((kc * 4 + q16) ^ (n & 7)) << 3)];
            }
#pragma unroll
            for (int tt = 0; tt < 4; ++tt)
                accg[tt] = __builtin_amdgcn_mfma_f32_16x16x32_bf16(af[kc], bf[tt],
                                                                   accg[tt], 0, 0, 0);
        }
        // sigmoid, scale by wavg (k of 2nd matmul == col of 1st), stash
#pragma unroll
        for (int tt = 0; tt < 4; ++tt)
#pragma unroll
            for (int r2 = 0; r2 < 4; ++r2) {
                const float x = accg[tt][r2] + gbv[tt];
                const float g = 1.f / (1.f + __expf(-x));
                GL(w, q16 * 4 + r2, tt * 16 + c16) = (__bf16)(g * wv[tt]);
            }
        __asm__ volatile("s_waitcnt lgkmcnt(0)" ::: "memory");
        bf16x8 a2[2];
#pragma unroll
        for (int kc = 0; kc < 2; ++kc)
            a2[kc] = *(const bf16x8*)&GL(w, c16, kc * 32 + q16 * 8);
        f32x4 acco[4] = {{0.f, 0.f, 0.f, 0.f}, {0.f, 0.f, 0.f, 0.f},
                         {0.f, 0.f, 0.f, 0.f}, {0.f, 0.f, 0.f, 0.f}};
#pragma unroll
        for (int kc = 0; kc < 2; ++kc) {
            bf16x8 bf[4];
#pragma unroll
            for (int tt = 0; tt < 4; ++tt) {
                const int n = tt * 16 + c16;
                bf[tt] = *(const bf16x8*)&owT[n * 64 + (((kc * 4 + q16) ^ (n & 7)) << 3)];
            }
#pragma unroll
            for (int tt = 0; tt < 4; ++tt)
                acco[tt] = __builtin_amdgcn_mfma_f32_16x16x32_bf16(a2[kc], bf[tt],
                                                                   acco[tt], 0, 0, 0);
        }
        __asm__ volatile("s_waitcnt lgkmcnt(0)" ::: "memory");  // gl reads done
        float* orow = out + (base_row + s * 16) * CC;
#pragma unroll
        for (int tt = 0; tt < 4; ++tt)
#pragma unroll
            for (int r2 = 0; r2 < 4; ++r2)
                orow[(size_t)(q16 * 4 + r2) * 64 + tt * 16 + c16] = acco[tt][r2] + obv[tt];
        cur0 = nxt0; cur1 = nxt1; cur2 = nxt2; cur3 = nxt3;
    }
#undef GL
#undef PVF
#undef RED
}

extern "C" void kernel_launch(void* const* d_in, const int* in_sizes, int n_in,
                              void* d_out, int out_size, void* d_ws, size_t ws_size,
                              hipStream_t stream) {
    const float* q_data = (const float*)d_in[0];
    const float* m_data = (const float*)d_in[1];
    const float* q_mask = (const float*)d_in[2];
    // d_in[3] = bias, ignored by the forward (AF2 quirk)
    const float* q_w = (const float*)d_in[4];
    const float* k_w = (const float*)d_in[5];
    const float* v_w = (const float*)d_in[6];
    const float* o_w = (const float*)d_in[7];
    const float* o_b = (const float*)d_in[8];
    const float* g_w = (const float*)d_in[9];
    const float* g_b = (const float*)d_in[10];
    float* out = (float*)d_out;
    (void)d_ws; (void)ws_size; (void)in_sizes; (void)n_in; (void)out_size;

    // one launch: block b handles batch b end-to-end (no workspace, no memset)
    hipLaunchKernelGGL(k_fused, dim3(BN), dim3(1024), 0, stream, q_data, m_data,
                       q_mask, q_w, k_w, v_w, o_w, o_b, g_w, g_b, out);
}